// Round 2
// baseline (442.380 us; speedup 1.0000x reference)
//
#include <hip/hip_runtime.h>
#include <math.h>

// HardMoE classifier: B=131072, D=1024, E=6, L=2, fp32.
// Wave-per-row, 2-row register blocking. Gate weights staged in LDS (24KB,
// shared by 8 waves/block) -> low VGPR -> 4 waves/SIMD for latency hiding.
// DPP cross-lane reductions (no LDS pipe use in reductions). f64 re-dot when
// top-2 gate gap < 1e-3 (argmax robustness vs numpy reference).

static constexpr int Bn = 131072;
static constexpr int En = 6;
static constexpr int WAVES_PER_BLOCK = 8;   // 512 threads
static constexpr int ROWS_PER_WAVE = 16;    // 8 iters x 2 rows

template <int CTRL>
__device__ __forceinline__ float dpp_row_add(float v) {
  return v + __int_as_float(__builtin_amdgcn_update_dpp(
                 0, __float_as_int(v), CTRL, 0xf, 0xf, true));
}

// Full 64-lane sum, broadcast via readlane(63) -> sgpr.
__device__ __forceinline__ float wave_sum_bcast(float v) {
  v = dpp_row_add<0x111>(v);  // row_shr:1
  v = dpp_row_add<0x112>(v);  // row_shr:2
  v = dpp_row_add<0x114>(v);  // row_shr:4
  v = dpp_row_add<0x118>(v);  // row_shr:8
  v = dpp_row_add<0x142>(v);  // row_bcast:15
  v = dpp_row_add<0x143>(v);  // row_bcast:31
  return __int_as_float(__builtin_amdgcn_readlane(__float_as_int(v), 63));
}

__device__ __forceinline__ float dot4(float4 a, float4 b) {
  return fmaf(a.x, b.x, fmaf(a.y, b.y, fmaf(a.z, b.z, a.w * b.w)));
}

__global__ __launch_bounds__(512, 4) void hardmoe_kernel(
    const float* __restrict__ cls, const float* __restrict__ gate_w,
    const float* __restrict__ gate_b, const float* __restrict__ expert_w,
    const float* __restrict__ expert_b, float* __restrict__ out) {
  __shared__ float4 ldsG4[1536];  // gate_w: 6x1024 floats = 24KB

  const int tid = threadIdx.x;
  const int lane = tid & 63;
  const int wv = tid >> 6;

  // Stage gate weights: 1536 float4 over 512 threads (3 each), coalesced.
  const float4* __restrict__ gw4 = (const float4*)gate_w;
#pragma unroll
  for (int k = 0; k < 3; ++k) ldsG4[tid + k * 512] = gw4[tid + k * 512];

  float gb[En];
#pragma unroll
  for (int e = 0; e < En; ++e) gb[e] = gate_b[e];

  __syncthreads();

  const float4* __restrict__ cls4 = (const float4*)cls;
  const float4* __restrict__ ew4 = (const float4*)expert_w;

  const int row0 = (blockIdx.x * WAVES_PER_BLOCK + wv) * ROWS_PER_WAVE;

  float4 c[2][4], p[2][4];
#pragma unroll
  for (int rr = 0; rr < 2; ++rr)
#pragma unroll
    for (int t = 0; t < 4; ++t)
      c[rr][t] = cls4[(size_t)(row0 + rr) * 256 + t * 64 + lane];

  for (int it = 0; it < ROWS_PER_WAVE / 2; ++it) {
    const int r0 = row0 + 2 * it;
    // Prefetch next row-pair (clamped; last pair re-reads, discarded).
    const int pr0 = (r0 + 2 <= Bn - 2) ? (r0 + 2) : (Bn - 2);
#pragma unroll
    for (int rr = 0; rr < 2; ++rr)
#pragma unroll
      for (int t = 0; t < 4; ++t)
        p[rr][t] = cls4[(size_t)(pr0 + rr) * 256 + t * 64 + lane];

    // ---- gate logits, both rows share each weight read ----
    float s[2][En];
#pragma unroll
    for (int e = 0; e < En; ++e) { s[0][e] = 0.f; s[1][e] = 0.f; }
#pragma unroll
    for (int e = 0; e < En; ++e)
#pragma unroll
      for (int t = 0; t < 4; ++t) {
        const float4 w = ldsG4[e * 256 + t * 64 + lane];
        s[0][e] += dot4(c[0][t], w);
        s[1][e] += dot4(c[1][t], w);
      }

    float lg[2][En];
#pragma unroll
    for (int e = 0; e < En; ++e) {
      lg[0][e] = wave_sum_bcast(s[0][e]) + gb[e];
      lg[1][e] = wave_sum_bcast(s[1][e]) + gb[e];
    }

    float o[2][2];
#pragma unroll
    for (int rr = 0; rr < 2; ++rr) {
      // argmax, first-occurrence tiebreak
      int best = 0;
      float bv = lg[rr][0], second = -INFINITY;
#pragma unroll
      for (int e = 1; e < En; ++e) {
        if (lg[rr][e] > bv) {
          second = bv; bv = lg[rr][e]; best = e;
        } else if (lg[rr][e] > second) {
          second = lg[rr][e];
        }
      }

      // Rare near-tie: f64 re-dot (wave-uniform cold branch).
      if (bv - second < 1e-3f) {
        double dbest = -1e300;
        int dbi = 0;
#pragma unroll
        for (int e = 0; e < En; ++e) {
          double ds = 0.0;
#pragma unroll
          for (int t = 0; t < 4; ++t) {
            const float4 w = ldsG4[e * 256 + t * 64 + lane];
            const float4 cc = c[rr][t];
            ds += (double)cc.x * (double)w.x;
            ds += (double)cc.y * (double)w.y;
            ds += (double)cc.z * (double)w.z;
            ds += (double)cc.w * (double)w.w;
          }
#pragma unroll
          for (int m = 1; m < 64; m <<= 1) ds += __shfl_xor(ds, m, 64);
          ds += (double)gb[e];
          if (ds > dbest) { dbest = ds; dbi = e; }
        }
        best = dbi;
      }

      // ---- chosen expert (weights from global: 48KB, L2-hot) ----
      const int ebase = best * 512;  // float4 idx of expert_w[best][0][0]
      float a0 = 0.f, a1 = 0.f;
#pragma unroll
      for (int t = 0; t < 4; ++t) {
        const float4 w0 = ew4[ebase + t * 64 + lane];
        const float4 w1 = ew4[ebase + 256 + t * 64 + lane];
        a0 += dot4(c[rr][t], w0);
        a1 += dot4(c[rr][t], w1);
      }
      o[rr][0] = wave_sum_bcast(a0) + expert_b[best * 2 + 0];
      o[rr][1] = wave_sum_bcast(a1) + expert_b[best * 2 + 1];
    }

    if (lane == 0)
      ((float4*)out)[r0 >> 1] = make_float4(o[0][0], o[0][1], o[1][0], o[1][1]);

#pragma unroll
    for (int rr = 0; rr < 2; ++rr)
#pragma unroll
      for (int t = 0; t < 4; ++t) c[rr][t] = p[rr][t];
  }
}

extern "C" void kernel_launch(void* const* d_in, const int* in_sizes, int n_in,
                              void* d_out, int out_size, void* d_ws,
                              size_t ws_size, hipStream_t stream) {
  const float* cls = (const float*)d_in[0];
  const float* gate_w = (const float*)d_in[1];
  const float* gate_b = (const float*)d_in[2];
  const float* expert_w = (const float*)d_in[3];
  const float* expert_b = (const float*)d_in[4];
  float* out = (float*)d_out;

  // 1024 blocks * 8 waves * 16 rows = 131072 rows exactly.
  hipLaunchKernelGGL(hardmoe_kernel, dim3(1024), dim3(512), 0, stream, cls,
                     gate_w, gate_b, expert_w, expert_b, out);
}

// Round 7
// 122.757 us; speedup vs baseline: 3.6037x; 3.6037x over previous
//
#include <hip/hip_runtime.h>
#include <math.h>

// HardMoE classifier: B=131072, D=1024, E=6, L=2, fp32.
// Wave-per-row, 2-row blocking. ALL weights LDS-resident (gate 24KB +
// expert 48KB + biases) so the cls HBM stream can't thrash them out of L2
// (round-1 pathology: per-row 8KB expert fetch missed L2 -> ~1GB fabric
// traffic + exposed ~900cyc latency after argmax). 512-thr blocks, 73KB LDS
// -> 2 blocks/CU = 16 waves/CU. No VGPR cap (round-2 pathology: launch_bounds
// reg cap -> 1.5GB scratch spills). DPP reductions; f64 tie fallback.
// (Rounds 3-6 were infra failures on one container — identical resubmit.)

static constexpr int Bn = 131072;
static constexpr int En = 6;

template <int CTRL>
__device__ __forceinline__ float dpp_row_add(float v) {
  return v + __int_as_float(__builtin_amdgcn_update_dpp(
                 0, __float_as_int(v), CTRL, 0xf, 0xf, true));
}

// Full 64-lane sum, broadcast via readlane(63) -> sgpr.
__device__ __forceinline__ float wave_sum_bcast(float v) {
  v = dpp_row_add<0x111>(v);  // row_shr:1
  v = dpp_row_add<0x112>(v);  // row_shr:2
  v = dpp_row_add<0x114>(v);  // row_shr:4
  v = dpp_row_add<0x118>(v);  // row_shr:8
  v = dpp_row_add<0x142>(v);  // row_bcast:15
  v = dpp_row_add<0x143>(v);  // row_bcast:31
  return __int_as_float(__builtin_amdgcn_readlane(__float_as_int(v), 63));
}

__device__ __forceinline__ float dot4(float4 a, float4 b) {
  return fmaf(a.x, b.x, fmaf(a.y, b.y, fmaf(a.z, b.z, a.w * b.w)));
}

__global__ __launch_bounds__(512) void hardmoe_kernel(
    const float* __restrict__ cls, const float* __restrict__ gate_w,
    const float* __restrict__ gate_b, const float* __restrict__ expert_w,
    const float* __restrict__ expert_b, float* __restrict__ out) {
  __shared__ float4 ldsG[1536];  // gate_w  6x1024    = 24 KB
  __shared__ float4 ldsE[3072];  // expert_w 6x2x1024 = 48 KB
  __shared__ float ldsGb[6];     // gate_b
  __shared__ float ldsEb[12];    // expert_b

  const int tid = threadIdx.x;
  const int lane = tid & 63;
  const int wv = tid >> 6;

  {
    const float4* __restrict__ gw4 = (const float4*)gate_w;
    const float4* __restrict__ ew4 = (const float4*)expert_w;
#pragma unroll
    for (int k = 0; k < 3; ++k) ldsG[tid + k * 512] = gw4[tid + k * 512];
#pragma unroll
    for (int k = 0; k < 6; ++k) ldsE[tid + k * 512] = ew4[tid + k * 512];
    if (tid < 6) ldsGb[tid] = gate_b[tid];
    else if (tid < 18) ldsEb[tid - 6] = expert_b[tid - 6];
  }
  __syncthreads();

  const float4* __restrict__ cls4 = (const float4*)cls;
  // 512 blocks * 8 waves * 32 rows = 131072 rows.
  const int row0 = (blockIdx.x * 8 + wv) * 32;

  float4 c[2][4], p[2][4];
#pragma unroll
  for (int rr = 0; rr < 2; ++rr)
#pragma unroll
    for (int t = 0; t < 4; ++t)
      c[rr][t] = cls4[(size_t)(row0 + rr) * 256 + t * 64 + lane];

  for (int it = 0; it < 16; ++it) {
    const int r0 = row0 + 2 * it;
    // Prefetch next pair (clamped; last iter re-reads in-bounds, discarded).
    const int pr0 = (r0 + 2 <= Bn - 2) ? (r0 + 2) : (Bn - 2);
#pragma unroll
    for (int rr = 0; rr < 2; ++rr)
#pragma unroll
      for (int t = 0; t < 4; ++t)
        p[rr][t] = cls4[(size_t)(pr0 + rr) * 256 + t * 64 + lane];

    // ---- gate logits, pair shares each LDS weight read ----
    float s0[En], s1[En];
#pragma unroll
    for (int e = 0; e < En; ++e) { s0[e] = 0.f; s1[e] = 0.f; }
#pragma unroll
    for (int e = 0; e < En; ++e)
#pragma unroll
      for (int t = 0; t < 4; ++t) {
        const float4 w = ldsG[e * 256 + t * 64 + lane];
        s0[e] += dot4(c[0][t], w);
        s1[e] += dot4(c[1][t], w);
      }

    float lg[2][En];
#pragma unroll
    for (int e = 0; e < En; ++e) {
      lg[0][e] = wave_sum_bcast(s0[e]) + ldsGb[e];
      lg[1][e] = wave_sum_bcast(s1[e]) + ldsGb[e];
    }

    float o[2][2];
#pragma unroll
    for (int rr = 0; rr < 2; ++rr) {
      // argmax, first-occurrence tiebreak
      int best = 0;
      float bv = lg[rr][0], second = -INFINITY;
#pragma unroll
      for (int e = 1; e < En; ++e) {
        if (lg[rr][e] > bv) {
          second = bv; bv = lg[rr][e]; best = e;
        } else if (lg[rr][e] > second) {
          second = lg[rr][e];
        }
      }

      // Rare near-tie: f64 re-dot from LDS (wave-uniform cold branch).
      if (bv - second < 1e-3f) {
        double dbest = -1e300;
        int dbi = 0;
#pragma unroll
        for (int e = 0; e < En; ++e) {
          double ds = 0.0;
#pragma unroll
          for (int t = 0; t < 4; ++t) {
            const float4 w = ldsG[e * 256 + t * 64 + lane];
            const float4 cc = c[rr][t];
            ds += (double)cc.x * (double)w.x;
            ds += (double)cc.y * (double)w.y;
            ds += (double)cc.z * (double)w.z;
            ds += (double)cc.w * (double)w.w;
          }
#pragma unroll
          for (int m = 1; m < 64; m <<= 1) ds += __shfl_xor(ds, m, 64);
          ds += (double)ldsGb[e];
          if (ds > dbest) { dbest = ds; dbi = e; }
        }
        best = dbi;
      }

      // ---- chosen expert from LDS (conflict-free b128 reads) ----
      const int ebase = best * 512;  // float4 idx of expert_w[best][0][0]
      float a0 = 0.f, a1 = 0.f;
#pragma unroll
      for (int t = 0; t < 4; ++t) {
        const float4 w0 = ldsE[ebase + t * 64 + lane];
        const float4 w1 = ldsE[ebase + 256 + t * 64 + lane];
        a0 += dot4(c[rr][t], w0);
        a1 += dot4(c[rr][t], w1);
      }
      o[rr][0] = wave_sum_bcast(a0) + ldsEb[best * 2 + 0];
      o[rr][1] = wave_sum_bcast(a1) + ldsEb[best * 2 + 1];
    }

    if (lane == 0)
      ((float4*)out)[r0 >> 1] = make_float4(o[0][0], o[0][1], o[1][0], o[1][1]);

#pragma unroll
    for (int rr = 0; rr < 2; ++rr)
#pragma unroll
      for (int t = 0; t < 4; ++t) c[rr][t] = p[rr][t];
  }
}

extern "C" void kernel_launch(void* const* d_in, const int* in_sizes, int n_in,
                              void* d_out, int out_size, void* d_ws,
                              size_t ws_size, hipStream_t stream) {
  const float* cls = (const float*)d_in[0];
  const float* gate_w = (const float*)d_in[1];
  const float* gate_b = (const float*)d_in[2];
  const float* expert_w = (const float*)d_in[3];
  const float* expert_b = (const float*)d_in[4];
  float* out = (float*)d_out;

  hipLaunchKernelGGL(hardmoe_kernel, dim3(512), dim3(512), 0, stream, cls,
                     gate_w, gate_b, expert_w, expert_b, out);
}